// Round 2
// baseline (929.269 us; speedup 1.0000x reference)
//
#include <hip/hip_runtime.h>

#define BB 512
#define TT 256
#define DD 512
#define HH 102
#define PP 51
#define NKEEP 128

typedef unsigned int u32;

// ---------------- Kernel 1: scores, sort, non-softmax, extra row, LN stats ----
__global__ __launch_bounds__(256) void k_score(
    const float* __restrict__ x, const float* __restrict__ ca,
    float* __restrict__ out, int* __restrict__ keepg,
    float* __restrict__ mug, float* __restrict__ ivg) {
  __shared__ float glo[DD];
  __shared__ float sc[TT];
  __shared__ float ss[TT];
  __shared__ int   perm[TT];
  __shared__ float wq[NKEEP];
  __shared__ float red[256];

  const int b = blockIdx.x;
  const int tid = threadIdx.x;
  const float* xb = x + (size_t)b * TT * DD;

  // phase 1: mean over tokens (each thread owns dims 2*tid, 2*tid+1)
  float a0 = 0.f, a1 = 0.f;
  for (int t = 0; t < TT; ++t) {
    float2 u = *(const float2*)(xb + t * DD + 2 * tid);
    a0 += u.x;
    a1 += u.y;
  }
  a0 *= (1.f / TT);
  a1 *= (1.f / TT);
  glo[2 * tid] = a0;
  glo[2 * tid + 1] = a1;
  red[tid] = a0 * a0 + a1 * a1;
  perm[tid] = tid;  // insurance: never leave perm uninitialized
  __syncthreads();
  for (int s = 128; s > 0; s >>= 1) {
    if (tid < s) red[tid] += red[tid + s];
    __syncthreads();
  }
  float inv = 1.f / fmaxf(sqrtf(red[0]), 1e-12f);
  glo[2 * tid] *= inv;
  glo[2 * tid + 1] *= inv;
  __syncthreads();

  // phase 2: per-token scores + LN stats (one wave per 64 tokens)
  const int wv = tid >> 6, lane = tid & 63;
  float gl[8];
#pragma unroll
  for (int j = 0; j < 8; ++j) gl[j] = glo[lane * 8 + j];

  for (int t = wv * 64; t < wv * 64 + 64; ++t) {
    const float* xr = xb + t * DD;
    float4 r0 = ((const float4*)xr)[lane * 2];
    float4 r1 = ((const float4*)xr)[lane * 2 + 1];
    float vs[8] = {r0.x, r0.y, r0.z, r0.w, r1.x, r1.y, r1.z, r1.w};
    float s1 = 0.f, s2 = 0.f, dt = 0.f;
#pragma unroll
    for (int j = 0; j < 8; ++j) {
      s1 += vs[j];
      s2 += vs[j] * vs[j];
      dt += vs[j] * gl[j];
    }
    for (int m = 32; m; m >>= 1) {
      s1 += __shfl_xor(s1, m);
      s2 += __shfl_xor(s2, m);
      dt += __shfl_xor(dt, m);
    }
    if (lane == 0) {
      float nr = sqrtf(s2);
      sc[t] = dt / fmaxf(nr, 1e-12f) + ca[b * TT + t];
      float mu = s1 * (1.f / DD);
      float var = s2 * (1.f / DD) - mu * mu;
      mug[b * TT + t] = mu;
      ivg[b * TT + t] = rsqrtf(var + 1e-5f);
    }
  }
  __syncthreads();

  // phase 3: stable descending rank (strict total order via index tiebreak)
  float st = sc[tid];
  int cnt = 0;
  for (int j = 0; j < TT; ++j) {
    float sj = sc[j];
    cnt += (sj > st) || (sj == st && j < tid);
  }
  perm[cnt] = tid;
  ss[cnt] = st;
  __syncthreads();

  // phase 4: softmax over non-kept (sorted positions 128..255)
  float mx = ss[NKEEP];
  if (tid < NKEEP) {
    float e = expf(ss[NKEEP + tid] - mx);
    wq[tid] = e;
    red[tid] = e;
  }
  __syncthreads();
  for (int s = 64; s > 0; s >>= 1) {
    if (tid < s) red[tid] += red[tid + s];
    __syncthreads();
  }
  float dn = 1.f / red[0];
  if (tid < NKEEP) {
    wq[tid] *= dn;
    keepg[b * NKEEP + tid] = perm[tid];
  }
  __syncthreads();

  // phase 5: extra = sum(non * w)  -> out row 51
  float e0 = 0.f, e1 = 0.f;
  for (int q = 0; q < NKEEP; ++q) {
    int tok = perm[NKEEP + q] & 255;
    float w = wq[q];
    float2 u = *(const float2*)(xb + tok * DD + 2 * tid);
    e0 += w * u.x;
    e1 += w * u.y;
  }
  float2 o = {e0, e1};
  ((float2*)(out + ((size_t)b * 52 + 51) * DD))[tid] = o;
}

// ---------------- Kernel 2: LN -> GEMM1 -> GELU -> GEMM2 -> softmax ----------
__global__ __launch_bounds__(256) void k_mlp(
    const float* __restrict__ x, const float* __restrict__ lng,
    const float* __restrict__ lnb, const float* __restrict__ w1,
    const float* __restrict__ b1, const float* __restrict__ w2,
    const float* __restrict__ b2, const float* __restrict__ scale,
    const int* __restrict__ keepg, const float* __restrict__ mug,
    const float* __restrict__ ivg, float* __restrict__ wtg) {
  __shared__ float smA[8704];        // ytile[128][68]  /  w2s[102*51]
  __shared__ float smB[7168];        // W1 tile[64][112] / wt[51][132]
  __shared__ float hbuf[128 * 113];  // h
  __shared__ float mus[128], ivs[128];
  __shared__ int keeps[128];
  __shared__ float b1s[112];
  __shared__ float b2s[64];
  __shared__ float lnGs[DD], lnBs[DD];
  __shared__ float sscale;

  const int b = blockIdx.x;
  const int tid = threadIdx.x;
  if (tid < 128) {
    int tok = keepg[b * NKEEP + tid] & 255;
    keeps[tid] = tok;
    mus[tid] = mug[b * TT + tok];
    ivs[tid] = ivg[b * TT + tok];
  }
  for (int i = tid; i < DD; i += 256) {
    lnGs[i] = lng[i];
    lnBs[i] = lnb[i];
  }
  if (tid < 112) b1s[tid] = (tid < HH) ? b1[tid] : 0.f;
  if (tid < 64) b2s[tid] = (tid < PP) ? b2[tid] : 0.f;
  if (tid == 0) sscale = scale[0];
  __syncthreads();

  const int ty = tid >> 4, tx = tid & 15;
  float acc[8][7];
#pragma unroll
  for (int rr = 0; rr < 8; ++rr)
#pragma unroll
    for (int jj = 0; jj < 7; ++jj) acc[rr][jj] = 0.f;

  const float* xb = x + (size_t)b * TT * DD;
  for (int dt = 0; dt < 8; ++dt) {
    // stage normalized y tile [128][64] (stride 68)
    for (int i = tid; i < 2048; i += 256) {
      int r = i >> 4, cq = i & 15;
      int tok = keeps[r];
      int d = dt * 64 + cq * 4;
      float4 u = *(const float4*)(xb + tok * DD + d);
      float mu = mus[r], iv = ivs[r];
      float4 yv;
      yv.x = (u.x - mu) * iv * lnGs[d] + lnBs[d];
      yv.y = (u.y - mu) * iv * lnGs[d + 1] + lnBs[d + 1];
      yv.z = (u.z - mu) * iv * lnGs[d + 2] + lnBs[d + 2];
      yv.w = (u.w - mu) * iv * lnGs[d + 3] + lnBs[d + 3];
      *(float4*)&smA[r * 68 + cq * 4] = yv;
    }
    // stage W1 tile [64][112] (cols >= HH zero)
    for (int i = tid; i < 64 * 112; i += 256) {
      int r = i / 112, j = i - r * 112;
      smB[i] = (j < HH) ? w1[(dt * 64 + r) * HH + j] : 0.f;
    }
    __syncthreads();
    for (int dd = 0; dd < 64; dd += 4) {
      float yv[8][4];
#pragma unroll
      for (int rr = 0; rr < 8; ++rr) {
        float4 t4 = *(const float4*)&smA[(ty + 16 * rr) * 68 + dd];
        yv[rr][0] = t4.x; yv[rr][1] = t4.y; yv[rr][2] = t4.z; yv[rr][3] = t4.w;
      }
#pragma unroll
      for (int u = 0; u < 4; ++u) {
        float wv[7];
#pragma unroll
        for (int jj = 0; jj < 7; ++jj) wv[jj] = smB[(dd + u) * 112 + tx + 16 * jj];
#pragma unroll
        for (int rr = 0; rr < 8; ++rr)
#pragma unroll
          for (int jj = 0; jj < 7; ++jj) acc[rr][jj] += yv[rr][u] * wv[jj];
      }
    }
    __syncthreads();
  }

  // bias + exact GELU -> hbuf
#pragma unroll
  for (int rr = 0; rr < 8; ++rr) {
    int r = ty + 16 * rr;
#pragma unroll
    for (int jj = 0; jj < 7; ++jj) {
      int j = tx + 16 * jj;
      float v = acc[rr][jj] + b1s[j];
      float g = 0.5f * v * (1.f + erff(v * 0.70710678118f));
      if (j < HH) hbuf[r * 113 + j] = g;
    }
  }
  // stage W2
  for (int i = tid; i < HH * PP; i += 256) smA[i] = w2[i];
  __syncthreads();

  // mm2: logits[k][p], k = ty+16rr, p = tx+16pp
  float ac2[8][4];
#pragma unroll
  for (int rr = 0; rr < 8; ++rr)
#pragma unroll
    for (int pp = 0; pp < 4; ++pp) ac2[rr][pp] = 0.f;
  for (int j = 0; j < HH; ++j) {
    float hv[8];
#pragma unroll
    for (int rr = 0; rr < 8; ++rr) hv[rr] = hbuf[(ty + 16 * rr) * 113 + j];
    float wv2[4];
#pragma unroll
    for (int pp = 0; pp < 4; ++pp) {
      int p = tx + 16 * pp;
      wv2[pp] = (p < PP) ? smA[j * PP + p] : 0.f;
    }
#pragma unroll
    for (int rr = 0; rr < 8; ++rr)
#pragma unroll
      for (int pp = 0; pp < 4; ++pp) ac2[rr][pp] += hv[rr] * wv2[pp];
  }
  float scv = sscale;
#pragma unroll
  for (int rr = 0; rr < 8; ++rr)
#pragma unroll
    for (int pp = 0; pp < 4; ++pp) {
      int p = tx + 16 * pp;
      if (p < PP) smB[p * 132 + (ty + 16 * rr)] = (ac2[rr][pp] + b2s[p]) * scv;
    }
  __syncthreads();

  // softmax over k for each p (wave per p row)
  const int wv_ = tid >> 6, lane = tid & 63;
  for (int p = wv_; p < PP; p += 4) {
    float v0 = smB[p * 132 + lane], v1 = smB[p * 132 + 64 + lane];
    float mx = fmaxf(v0, v1);
    for (int m = 32; m; m >>= 1) mx = fmaxf(mx, __shfl_xor(mx, m));
    float e0 = expf(v0 - mx), e1 = expf(v1 - mx);
    float s = e0 + e1;
    for (int m = 32; m; m >>= 1) s += __shfl_xor(s, m);
    float is = 1.f / s;
    smB[p * 132 + lane] = e0 * is;
    smB[p * 132 + 64 + lane] = e1 * is;
  }
  __syncthreads();
  for (int i = tid; i < PP * NKEEP; i += 256) {
    int p = i >> 7, k = i & 127;
    wtg[(size_t)b * PP * NKEEP + i] = smB[p * 132 + k];
  }
}

// ---------------- Kernel 3: aggr = w @ sel -> out rows 0..50 -----------------
__global__ __launch_bounds__(256) void k_aggr(
    const float* __restrict__ x, const int* __restrict__ keepg,
    const float* __restrict__ wtg, float* __restrict__ out) {
  __shared__ float wts[PP * NKEEP];
  __shared__ float stile[32 * 260];
  __shared__ int keeps[NKEEP];
  const int bid = blockIdx.x;
  const int b = bid >> 1, ch = bid & 1;
  const int c0 = ch * 256;
  const int tid = threadIdx.x;
  if (tid < NKEEP) keeps[tid] = keepg[b * NKEEP + tid] & 255;
  for (int i = tid; i < PP * NKEEP; i += 256) wts[i] = wtg[(size_t)b * PP * NKEEP + i];
  __syncthreads();
  const int tx = tid & 63, ty = tid >> 6;
  float acc[13][4];
#pragma unroll
  for (int pp = 0; pp < 13; ++pp)
#pragma unroll
    for (int u = 0; u < 4; ++u) acc[pp][u] = 0.f;
  const float* xb = x + (size_t)b * TT * DD;
  for (int kt = 0; kt < 4; ++kt) {
    for (int i = tid; i < 2048; i += 256) {
      int r = i >> 6, cq = i & 63;
      int tok = keeps[kt * 32 + r];
      float4 v = *(const float4*)(xb + tok * DD + c0 + cq * 4);
      *(float4*)&stile[r * 260 + cq * 4] = v;
    }
    __syncthreads();
    for (int kk = 0; kk < 32; ++kk) {
      float4 sv = *(const float4*)&stile[kk * 260 + tx * 4];
      int k = kt * 32 + kk;
#pragma unroll
      for (int pp = 0; pp < 13; ++pp) {
        int p = ty + 4 * pp;
        float w = (p < PP) ? wts[p * NKEEP + k] : 0.f;
        acc[pp][0] += w * sv.x;
        acc[pp][1] += w * sv.y;
        acc[pp][2] += w * sv.z;
        acc[pp][3] += w * sv.w;
      }
    }
    __syncthreads();
  }
#pragma unroll
  for (int pp = 0; pp < 13; ++pp) {
    int p = ty + 4 * pp;
    if (p < PP) {
      float4 o = {acc[pp][0], acc[pp][1], acc[pp][2], acc[pp][3]};
      ((float4*)(out + ((size_t)b * 52 + p) * DD + c0))[tx] = o;
    }
  }
}

extern "C" void kernel_launch(void* const* d_in, const int* in_sizes, int n_in,
                              void* d_out, int out_size, void* d_ws, size_t ws_size,
                              hipStream_t stream) {
  const float* x = (const float*)d_in[0];
  const float* ca = (const float*)d_in[1];
  const float* lng = (const float*)d_in[2];
  const float* lnb = (const float*)d_in[3];
  const float* w1 = (const float*)d_in[4];
  const float* b1 = (const float*)d_in[5];
  const float* w2 = (const float*)d_in[6];
  const float* b2 = (const float*)d_in[7];
  const float* scale = (const float*)d_in[8];
  float* out = (float*)d_out;

  char* ws = (char*)d_ws;
  int* keepg = (int*)ws;                                  // B*128 ints
  float* mug = (float*)(ws + (size_t)BB * NKEEP * 4);     // B*T
  float* ivg = mug + (size_t)BB * TT;                     // B*T
  float* wtg = ivg + (size_t)BB * TT;                     // B*51*128

  k_score<<<BB, 256, 0, stream>>>(x, ca, out, keepg, mug, ivg);
  k_mlp<<<BB, 256, 0, stream>>>(x, lng, lnb, w1, b1, w2, b2, scale, keepg, mug,
                                ivg, wtg);
  k_aggr<<<BB * 2, 256, 0, stream>>>(x, keepg, wtg, out);
}

// Round 3
// 679.325 us; speedup vs baseline: 1.3679x; 1.3679x over previous
//
#include <hip/hip_runtime.h>

#define BB 512
#define TT 256
#define DD 512
#define HH 102
#define PP 51
#define NKEEP 128

typedef unsigned short u16;
typedef unsigned int u32;

static __device__ __forceinline__ float bf2f(u16 u) {
  u32 v = ((u32)u) << 16;
  float f;
  __builtin_memcpy(&f, &v, 4);
  return f;
}
static __device__ __forceinline__ u16 f2bf(float f) {
  u32 v;
  __builtin_memcpy(&v, &f, 4);
  u32 r = v + 0x7fffu + ((v >> 16) & 1u);
  return (u16)(r >> 16);
}

// ---------------- Kernel 1: scores, sort, non-softmax, extra row, LN stats ----
__global__ __launch_bounds__(1024, 4) void k_score(
    const float* __restrict__ x, const float* __restrict__ ca,
    float* __restrict__ out, int* __restrict__ keepg,
    float* __restrict__ mug, float* __restrict__ ivg) {
  __shared__ float part[8 * 512];  // 16 KB; aliased as pc[] in phase 3
  __shared__ float glo[DD];
  __shared__ float sc[TT];
  __shared__ float ss[TT];
  __shared__ int perm[TT];
  __shared__ float wq[NKEEP];
  __shared__ float red[128];
  int* pc = (int*)part;

  const int b = blockIdx.x;
  const int tid = threadIdx.x;
  const float* xb = x + (size_t)b * TT * DD;

  // phase 1: mean over tokens, 8-way token-split partials
  {
    int c4 = (tid & 127) * 4, tg = tid >> 7;
    float4 a = {0.f, 0.f, 0.f, 0.f};
    const float* p0 = xb + tg * 32 * DD + c4;
    for (int t = 0; t < 32; ++t) {
      float4 v = *(const float4*)(p0 + t * DD);
      a.x += v.x; a.y += v.y; a.z += v.z; a.w += v.w;
    }
    *(float4*)&part[tg * 512 + c4] = a;
  }
  __syncthreads();
  if (tid < 128) {
    int c4 = tid * 4;
    float4 m = {0.f, 0.f, 0.f, 0.f};
    for (int g = 0; g < 8; ++g) {
      float4 v = *(const float4*)&part[g * 512 + c4];
      m.x += v.x; m.y += v.y; m.z += v.z; m.w += v.w;
    }
    m.x *= (1.f / TT); m.y *= (1.f / TT); m.z *= (1.f / TT); m.w *= (1.f / TT);
    *(float4*)&glo[c4] = m;
    red[tid] = m.x * m.x + m.y * m.y + m.z * m.z + m.w * m.w;
  }
  __syncthreads();
  for (int s = 64; s > 0; s >>= 1) {
    if (tid < s) red[tid] += red[tid + s];
    __syncthreads();
  }
  if (tid < 128) {
    float inv = 1.f / fmaxf(sqrtf(red[0]), 1e-12f);
    int c4 = tid * 4;
    float4 m = *(float4*)&glo[c4];
    m.x *= inv; m.y *= inv; m.z *= inv; m.w *= inv;
    *(float4*)&glo[c4] = m;
  }
  __syncthreads();

  // phase 2: per-token scores + LN stats (16 waves x 16 tokens)
  {
    const int w = tid >> 6, lane = tid & 63;
    float gl[8];
#pragma unroll
    for (int j = 0; j < 8; ++j) gl[j] = glo[lane * 8 + j];
    for (int i = 0; i < 16; ++i) {
      int t = w * 16 + i;
      const float* xr = xb + t * DD + lane * 8;
      float4 r0 = *(const float4*)xr;
      float4 r1 = *(const float4*)(xr + 4);
      float vs[8] = {r0.x, r0.y, r0.z, r0.w, r1.x, r1.y, r1.z, r1.w};
      float s1 = 0.f, s2 = 0.f, dt = 0.f;
#pragma unroll
      for (int j = 0; j < 8; ++j) {
        s1 += vs[j];
        s2 += vs[j] * vs[j];
        dt += vs[j] * gl[j];
      }
      for (int m = 32; m; m >>= 1) {
        s1 += __shfl_xor(s1, m);
        s2 += __shfl_xor(s2, m);
        dt += __shfl_xor(dt, m);
      }
      if (lane == 0) {
        sc[t] = dt / fmaxf(sqrtf(s2), 1e-12f) + ca[b * TT + t];
        float mu = s1 * (1.f / DD);
        float var = s2 * (1.f / DD) - mu * mu;
        mug[b * TT + t] = mu;
        ivg[b * TT + t] = rsqrtf(var + 1e-5f);
      }
    }
  }
  __syncthreads();

  // phase 3: stable descending rank, distributed over 4 j-chunks
  {
    int t = tid & 255, ch = tid >> 8;
    float st = sc[t];
    int cnt = 0;
    for (int j = ch * 64; j < ch * 64 + 64; ++j) {
      float sj = sc[j];
      cnt += (sj > st) || (sj == st && j < t);
    }
    pc[ch * 256 + t] = cnt;
  }
  __syncthreads();
  if (tid < 256) {
    int rank = pc[tid] + pc[256 + tid] + pc[512 + tid] + pc[768 + tid];
    perm[rank] = tid;
    ss[rank] = sc[tid];
  }
  __syncthreads();

  // phase 4: softmax over non-kept (sorted 128..255); max = ss[128] (sorted)
  if (tid < 128) {
    float e = expf(ss[NKEEP + tid] - ss[NKEEP]);
    wq[tid] = e;
    red[tid] = e;
  }
  __syncthreads();
  for (int s = 64; s > 0; s >>= 1) {
    if (tid < s) red[tid] += red[tid + s];
    __syncthreads();
  }
  if (tid < 128) {
    wq[tid] *= (1.f / red[0]);
    keepg[b * NKEEP + tid] = perm[tid];
  }
  __syncthreads();

  // phase 5: extra = sum(non * w) -> out row 51 (8-way token-split)
  {
    int c4 = (tid & 127) * 4, tg = tid >> 7;
    float4 a = {0.f, 0.f, 0.f, 0.f};
    for (int q = tg * 16; q < tg * 16 + 16; ++q) {
      int tok = perm[NKEEP + q] & 255;
      float w = wq[q];
      float4 v = *(const float4*)(xb + tok * DD + c4);
      a.x += w * v.x; a.y += w * v.y; a.z += w * v.z; a.w += w * v.w;
    }
    *(float4*)&part[tg * 512 + c4] = a;
  }
  __syncthreads();
  if (tid < 128) {
    int c4 = tid * 4;
    float4 m = {0.f, 0.f, 0.f, 0.f};
    for (int g = 0; g < 8; ++g) {
      float4 v = *(const float4*)&part[g * 512 + c4];
      m.x += v.x; m.y += v.y; m.z += v.z; m.w += v.w;
    }
    *(float4*)(out + ((size_t)b * 52 + 51) * DD + c4) = m;
  }
}

// ------ Kernel 2 (fused): LN -> GEMM1 -> GELU -> GEMM2 -> softmax -> aggr ----
// LDS union (floats):
//  phase A: ytile[128][68] @0 (8704) | w1t[64][112] @8704 (7168)   = 15872
//  phase B: h bf16 [128][104] @0 (=6656 floats) | w2s[102*51] @6656 (5202)
//  phase C: wt[51][132] @0 (6732) | stile[16][516] @6732 (8256)    = 14988
__global__ __launch_bounds__(512, 4) void k_fused(
    const float* __restrict__ x, const float* __restrict__ lng,
    const float* __restrict__ lnb, const float* __restrict__ w1,
    const float* __restrict__ b1, const float* __restrict__ w2,
    const float* __restrict__ b2, const float* __restrict__ scale,
    const int* __restrict__ keepg, const float* __restrict__ mug,
    const float* __restrict__ ivg, float* __restrict__ out) {
  __shared__ float U[15872];
  __shared__ float lnGs[DD], lnBs[DD];
  __shared__ float mus[128], ivs[128];
  __shared__ int keeps[128];
  __shared__ float b1s[112], b2s[64];
  __shared__ float sscale;

  float* ytile = U;          // [128][68]
  float* w1t = U + 8704;     // [64][112]
  u16* hb = (u16*)U;         // [128][104] bf16
  float* w2s = U + 6656;     // [102][51]
  float* wt = U;             // [51][132]
  float* stile = U + 6732;   // [16][516]

  const int b = blockIdx.x;
  const int tid = threadIdx.x;

  if (tid < 128) {
    int tok = keepg[b * NKEEP + tid] & 255;
    keeps[tid] = tok;
    mus[tid] = mug[b * TT + tok];
    ivs[tid] = ivg[b * TT + tok];
  }
  for (int i = tid; i < DD; i += 512) {
    lnGs[i] = lng[i];
    lnBs[i] = lnb[i];
  }
  if (tid < 112) b1s[tid] = (tid < HH) ? b1[tid] : 0.f;
  if (tid < 64) b2s[tid] = (tid < PP) ? b2[tid] : 0.f;
  if (tid == 0) sscale = scale[0];
  __syncthreads();

  const int ty = tid >> 4, tx = tid & 15;  // ty 0..31, tx 0..15
  float acc[4][7];
#pragma unroll
  for (int rr = 0; rr < 4; ++rr)
#pragma unroll
    for (int jj = 0; jj < 7; ++jj) acc[rr][jj] = 0.f;

  const float* xb = x + (size_t)b * TT * DD;
  // ---- mm1: y(128x512) @ W1(512x112pad), 8 d-tiles of 64 ----
  for (int dt8 = 0; dt8 < 8; ++dt8) {
    for (int i = tid; i < 2048; i += 512) {  // ytile stage: 128x64 as float4
      int r = i >> 4, cq = i & 15;
      int tok = keeps[r];
      int d = dt8 * 64 + cq * 4;
      float4 u = *(const float4*)(xb + tok * DD + d);
      float mu = mus[r], iv = ivs[r];
      float4 yv;
      yv.x = (u.x - mu) * iv * lnGs[d] + lnBs[d];
      yv.y = (u.y - mu) * iv * lnGs[d + 1] + lnBs[d + 1];
      yv.z = (u.z - mu) * iv * lnGs[d + 2] + lnBs[d + 2];
      yv.w = (u.w - mu) * iv * lnGs[d + 3] + lnBs[d + 3];
      *(float4*)&ytile[r * 68 + cq * 4] = yv;
    }
    for (int i = tid; i < 7168; i += 512) {  // W1 tile 64x112
      int r = i / 112, j = i - r * 112;
      w1t[i] = (j < HH) ? w1[(dt8 * 64 + r) * HH + j] : 0.f;
    }
    __syncthreads();
    for (int dd = 0; dd < 64; dd += 4) {
      float yv[4][4];
#pragma unroll
      for (int rr = 0; rr < 4; ++rr) {
        float4 t4 = *(const float4*)&ytile[(ty + 32 * rr) * 68 + dd];
        yv[rr][0] = t4.x; yv[rr][1] = t4.y; yv[rr][2] = t4.z; yv[rr][3] = t4.w;
      }
#pragma unroll
      for (int u = 0; u < 4; ++u) {
        float wv[7];
#pragma unroll
        for (int jj = 0; jj < 7; ++jj) wv[jj] = w1t[(dd + u) * 112 + tx + 16 * jj];
#pragma unroll
        for (int rr = 0; rr < 4; ++rr)
#pragma unroll
          for (int jj = 0; jj < 7; ++jj) acc[rr][jj] += yv[rr][u] * wv[jj];
      }
    }
    __syncthreads();
  }

  // ---- bias + exact GELU -> h (bf16 in LDS) ; stage W2 ----
#pragma unroll
  for (int rr = 0; rr < 4; ++rr) {
    int r = ty + 32 * rr;
#pragma unroll
    for (int jj = 0; jj < 7; ++jj) {
      int j = tx + 16 * jj;
      float v = acc[rr][jj] + b1s[j];
      float g = 0.5f * v * (1.f + erff(v * 0.70710678118f));
      if (j < HH) hb[r * 104 + j] = f2bf(g);
    }
  }
  for (int i = tid; i < HH * PP; i += 512) w2s[i] = w2[i];
  __syncthreads();

  // ---- mm2: logits[k][p] = h(128x102) @ W2(102x51) ----
  float ac2[4][4];
#pragma unroll
  for (int rr = 0; rr < 4; ++rr)
#pragma unroll
    for (int pp = 0; pp < 4; ++pp) ac2[rr][pp] = 0.f;
  for (int j = 0; j < HH; ++j) {
    float hv[4];
#pragma unroll
    for (int rr = 0; rr < 4; ++rr) hv[rr] = bf2f(hb[(ty + 32 * rr) * 104 + j]);
    float wv2[4];
#pragma unroll
    for (int pp = 0; pp < 4; ++pp) {
      int p = tx + 16 * pp;
      wv2[pp] = (p < PP) ? w2s[j * PP + p] : 0.f;
    }
#pragma unroll
    for (int rr = 0; rr < 4; ++rr)
#pragma unroll
      for (int pp = 0; pp < 4; ++pp) ac2[rr][pp] += hv[rr] * wv2[pp];
  }
  __syncthreads();  // all reads of hb/w2s done before wt overwrites them
  {
    float scv = sscale;
#pragma unroll
    for (int rr = 0; rr < 4; ++rr)
#pragma unroll
      for (int pp = 0; pp < 4; ++pp) {
        int p = tx + 16 * pp;
        if (p < PP) wt[p * 132 + (ty + 32 * rr)] = (ac2[rr][pp] + b2s[p]) * scv;
      }
  }
  __syncthreads();

  // ---- softmax over k for each p (8 waves) ----
  {
    const int wv_ = tid >> 6, lane = tid & 63;
    for (int p = wv_; p < PP; p += 8) {
      float v0 = wt[p * 132 + lane], v1 = wt[p * 132 + 64 + lane];
      float mx = fmaxf(v0, v1);
      for (int m = 32; m; m >>= 1) mx = fmaxf(mx, __shfl_xor(mx, m));
      float e0 = expf(v0 - mx), e1 = expf(v1 - mx);
      float s = e0 + e1;
      for (int m = 32; m; m >>= 1) s += __shfl_xor(s, m);
      float is = 1.f / s;
      wt[p * 132 + lane] = e0 * is;
      wt[p * 132 + 64 + lane] = e1 * is;
    }
  }
  __syncthreads();

  // ---- aggr: out[p][c] = sum_k wt[p][k] * x[keep[k]][c] ----
  {
    const int cq = tid & 127, pg = tid >> 7;  // 4 cols per thread, 13 p's
    float4 a2[13];
#pragma unroll
    for (int pp = 0; pp < 13; ++pp) a2[pp] = {0.f, 0.f, 0.f, 0.f};
    for (int kt = 0; kt < 8; ++kt) {
      for (int i = tid; i < 2048; i += 512) {  // stage 16 rows x 512 cols
        int r = i >> 7, cc = i & 127;
        float4 v = *(const float4*)(xb + keeps[kt * 16 + r] * DD + cc * 4);
        *(float4*)&stile[r * 516 + cc * 4] = v;
      }
      __syncthreads();
      for (int kk = 0; kk < 16; ++kk) {
        float4 sv = *(const float4*)&stile[kk * 516 + cq * 4];
        int k = kt * 16 + kk;
#pragma unroll
        for (int pp = 0; pp < 13; ++pp) {
          int p = pg + 4 * pp;
          float w = wt[(p < PP ? p : PP - 1) * 132 + k];
          a2[pp].x += w * sv.x;
          a2[pp].y += w * sv.y;
          a2[pp].z += w * sv.z;
          a2[pp].w += w * sv.w;
        }
      }
      __syncthreads();
    }
#pragma unroll
    for (int pp = 0; pp < 13; ++pp) {
      int p = pg + 4 * pp;
      if (p < PP)
        *(float4*)(out + ((size_t)b * 52 + p) * DD + cq * 4) = a2[pp];
    }
  }
}

extern "C" void kernel_launch(void* const* d_in, const int* in_sizes, int n_in,
                              void* d_out, int out_size, void* d_ws, size_t ws_size,
                              hipStream_t stream) {
  const float* x = (const float*)d_in[0];
  const float* ca = (const float*)d_in[1];
  const float* lng = (const float*)d_in[2];
  const float* lnb = (const float*)d_in[3];
  const float* w1 = (const float*)d_in[4];
  const float* b1 = (const float*)d_in[5];
  const float* w2 = (const float*)d_in[6];
  const float* b2 = (const float*)d_in[7];
  const float* scale = (const float*)d_in[8];
  float* out = (float*)d_out;

  char* ws = (char*)d_ws;
  int* keepg = (int*)ws;                               // B*128 ints
  float* mug = (float*)(ws + (size_t)BB * NKEEP * 4);  // B*T
  float* ivg = mug + (size_t)BB * TT;                  // B*T

  k_score<<<BB, 1024, 0, stream>>>(x, ca, out, keepg, mug, ivg);
  k_fused<<<BB, 512, 0, stream>>>(x, lng, lnb, w1, b1, w2, b2, scale, keepg,
                                  mug, ivg, out);
}